// Round 3
// baseline (46.972 us; speedup 1.0000x reference)
//
#include <hip/hip_runtime.h>
#include <math.h>

namespace {

constexpr int NLAY = 10;
constexpr int NQB  = 4;
constexpr int NB   = 16;   // batch
constexpr int HH   = 128;
constexpr int WW   = 128;
constexpr int DI   = HH - 1;   // 127
constexpr int DJ   = WW - 1;   // 127
constexpr int NPATCH = NB * DI * DJ;   // 258064

// Combined CZ(0,1)*CZ(2,3)*CZ(1,2) sign per basis index (bit3=a,...,bit0=d)
constexpr unsigned SIGNMASK = 0xB848u;

__device__ __forceinline__ float2 cmul(float2 a, float2 b) {
    return make_float2(fmaf(a.x, b.x, -a.y * b.y), fmaf(a.x, b.y, a.y * b.x));
}
__device__ __forceinline__ float2 cadd(float2 a, float2 b) {
    return make_float2(a.x + b.x, a.y + b.y);
}
__device__ __forceinline__ void mm2(float2* D, const float2* A, const float2* B) {
    D[0] = cadd(cmul(A[0], B[0]), cmul(A[1], B[2]));
    D[1] = cadd(cmul(A[0], B[1]), cmul(A[1], B[3]));
    D[2] = cadd(cmul(A[2], B[0]), cmul(A[3], B[2]));
    D[3] = cadd(cmul(A[2], B[1]), cmul(A[3], B[3]));
}

// ---- setup: build the full-circuit 16x16 unitary M (column per thread) ----
__global__ void build_M_kernel(
    const float* __restrict__ gates,    // [10,4,3] one-hot
    const float* __restrict__ angles,   // [10,4]
    float2* __restrict__ M)             // [16][16] row-major: M[o*16+j]
{
    const int j = threadIdx.x;
    if (j >= 16) return;

    float2 st[16];
#pragma unroll
    for (int k = 0; k < 16; ++k) st[k] = make_float2(0.f, 0.f);
    st[j] = make_float2(1.f, 0.f);

#pragma unroll 1
    for (int l = 0; l < NLAY; ++l) {
#pragma unroll
        for (int q = 0; q < NQB; ++q) {
            const int g = l * NQB + q;
            const float ang = angles[g];
            const float ax = gates[g * 3 + 0] * ang * 0.5f;
            const float ay = gates[g * 3 + 1] * ang * 0.5f;
            const float az = gates[g * 3 + 2] * ang * 0.5f;
            float sx, cx, sy, cy, sz, cz;
            sincosf(ax, &sx, &cx);
            sincosf(ay, &sy, &cy);
            sincosf(az, &sz, &cz);
            float2 RX[4] = {{cx, 0.f}, {0.f, -sx}, {0.f, -sx}, {cx, 0.f}};
            float2 RY[4] = {{cy, 0.f}, {-sy, 0.f}, {sy, 0.f}, {cy, 0.f}};
            float2 RZ[4] = {{cz, -sz}, {0.f, 0.f}, {0.f, 0.f}, {cz, sz}};
            float2 Mt[4], U[4];
            mm2(Mt, RY, RX);
            mm2(U, RZ, Mt);

            const int s = 8 >> q;
#pragma unroll
            for (int p = 0; p < 8; ++p) {
                const int i0 = ((p & ~(s - 1)) << 1) | (p & (s - 1));
                const int i1 = i0 + s;
                const float2 va = st[i0];
                const float2 vb = st[i1];
                st[i0] = cadd(cmul(U[0], va), cmul(U[1], vb));
                st[i1] = cadd(cmul(U[2], va), cmul(U[3], vb));
            }
        }
#pragma unroll
        for (int k = 0; k < 16; ++k) {
            if ((SIGNMASK >> k) & 1u) {
                st[k].x = -st[k].x;
                st[k].y = -st[k].y;
            }
        }
    }

#pragma unroll
    for (int o = 0; o < 16; ++o) M[o * 16 + j] = st[o];
}

// ---- main: init product state, 16x16 matvec from LDS, Z expectations ----
__global__ __launch_bounds__(256) void qcnn_main_kernel(
    const float* __restrict__ images,   // [16,128,128,3]
    const float4* __restrict__ M4,      // [16][16] complex as 128 float4
    float* __restrict__ out)            // [16,127,127,4]
{
    __shared__ float4 Msh[128];   // 2 KB: M row-major, 2 complex per float4

    const int t = threadIdx.x;
    if (t < 128) Msh[t] = M4[t];
    __syncthreads();

    const int n = blockIdx.x * blockDim.x + t;
    if (n >= NPATCH) return;

    const int bimg = n / (DI * DJ);
    const int rem  = n - bimg * (DI * DJ);
    const int pi   = rem / DJ;
    const int pj   = rem - pi * DJ;

    const float* base = images + ((size_t)(bimg * HH + pi) * WW + pj) * 3;

    // per-qubit initial states from pixel RGB
    float2 S[NQB][2];
#pragma unroll
    for (int a = 0; a < 2; ++a) {
#pragma unroll
        for (int b = 0; b < 2; ++b) {
            const float* px = base + ((size_t)a * WW + b) * 3;
            const float d0 = px[0], d1 = px[1], d2 = px[2];
            const float al = 0.5f * (d0 + d2);   // (phi+omega)/(2*pi)
            const float be = 0.5f * (d2 - d0);   // (omega-phi)/(2*pi)
            const float th = 0.5f * d1;          // theta/(2*pi)
            float sa, ca, sb, cb, stt, ctt;
            sincospif(al, &sa, &ca);
            sincospif(be, &sb, &cb);
            sincospif(th, &stt, &ctt);
            const int q = a * 2 + b;
            S[q][0] = make_float2(ca * ctt, -sa * ctt);
            S[q][1] = make_float2(cb * stt,  sb * stt);
        }
    }

    // product state st = S0 (x) S1 (x) S2 (x) S3
    float2 st[16];
#pragma unroll
    for (int a = 0; a < 2; ++a) {
#pragma unroll
        for (int b = 0; b < 2; ++b) {
            const float2 ab = cmul(S[0][a], S[1][b]);
#pragma unroll
            for (int c = 0; c < 2; ++c) {
                const float2 abc = cmul(ab, S[2][c]);
#pragma unroll
                for (int d = 0; d < 2; ++d) {
                    st[a * 8 + b * 4 + c * 2 + d] = cmul(abc, S[3][d]);
                }
            }
        }
    }

    // y_o = sum_k M[o][k] * st[k]; probs + Z expectations on the fly.
    // M reads are uniform-address LDS broadcasts (no bank conflicts).
    float e0 = 0.f, e1 = 0.f, e2 = 0.f, e3 = 0.f;
#pragma unroll
    for (int o = 0; o < 16; ++o) {
        float accx = 0.f, accy = 0.f;
#pragma unroll
        for (int kk = 0; kk < 8; ++kk) {
            const float4 m = Msh[o * 8 + kk];   // {Re k, Im k, Re k+1, Im k+1}
            const float2 s0 = st[2 * kk];
            const float2 s1 = st[2 * kk + 1];
            accx = fmaf(m.x, s0.x, accx);
            accx = fmaf(-m.y, s0.y, accx);
            accy = fmaf(m.x, s0.y, accy);
            accy = fmaf(m.y, s0.x, accy);
            accx = fmaf(m.z, s1.x, accx);
            accx = fmaf(-m.w, s1.y, accx);
            accy = fmaf(m.z, s1.y, accy);
            accy = fmaf(m.w, s1.x, accy);
        }
        const float pr = fmaf(accx, accx, accy * accy);
        e0 += (o & 8) ? -pr : pr;
        e1 += (o & 4) ? -pr : pr;
        e2 += (o & 2) ? -pr : pr;
        e3 += (o & 1) ? -pr : pr;
    }

    float4 res = make_float4(e0, e1, e2, e3);
    *reinterpret_cast<float4*>(out + (size_t)n * 4) = res;
}

}  // namespace

extern "C" void kernel_launch(void* const* d_in, const int* in_sizes, int n_in,
                              void* d_out, int out_size, void* d_ws, size_t ws_size,
                              hipStream_t stream) {
    const float* images = (const float*)d_in[0];
    const float* gates  = (const float*)d_in[1];
    const float* angles = (const float*)d_in[2];
    float* out = (float*)d_out;
    float2* M = (float2*)d_ws;   // 16*16*8 = 2048 bytes

    build_M_kernel<<<1, 64, 0, stream>>>(gates, angles, M);

    const int block = 256;
    const int grid = (NPATCH + block - 1) / block;
    qcnn_main_kernel<<<grid, block, 0, stream>>>(images, (const float4*)M, out);
}

// Round 4
// 24.416 us; speedup vs baseline: 1.9238x; 1.9238x over previous
//
#include <hip/hip_runtime.h>
#include <math.h>

namespace {

constexpr int NLAY = 10;
constexpr int NQB  = 4;
constexpr int NB   = 16;   // batch
constexpr int HH   = 128;
constexpr int WW   = 128;
constexpr int DI   = HH - 1;   // 127
constexpr int DJ   = WW - 1;   // 127
constexpr int NPATCH = NB * DI * DJ;   // 258064

// Combined CZ(0,1)*CZ(2,3)*CZ(1,2) sign per basis index (bit3=a,...,bit0=d)
constexpr unsigned SIGNMASK = 0xB848u;

__device__ __forceinline__ float2 cmul(float2 a, float2 b) {
    return make_float2(fmaf(a.x, b.x, -a.y * b.y), fmaf(a.x, b.y, a.y * b.x));
}
__device__ __forceinline__ float2 cadd(float2 a, float2 b) {
    return make_float2(a.x + b.x, a.y + b.y);
}
__device__ __forceinline__ void mm2(float2* D, const float2* A, const float2* B) {
    D[0] = cadd(cmul(A[0], B[0]), cmul(A[1], B[2]));
    D[1] = cadd(cmul(A[0], B[1]), cmul(A[1], B[3]));
    D[2] = cadd(cmul(A[2], B[0]), cmul(A[3], B[2]));
    D[3] = cadd(cmul(A[2], B[1]), cmul(A[3], B[3]));
}

// ---- setup: build full-circuit 16x16 unitary M, parallel over 256 threads --
// Stage A: 40 threads -> per-(layer,qubit) 2x2 unitaries (parallel).
// Per layer: 256 threads -> one Kron entry each (3 cmul) + CZ row sign,
//            then M <- L * M as a 16x16x16 LDS product (16 cmul/thread).
__global__ __launch_bounds__(256) void build_M_kernel(
    const float* __restrict__ gates,    // [10,4,3] one-hot
    const float* __restrict__ angles,   // [10,4]
    float2* __restrict__ M_out)         // [16][16] row-major
{
    __shared__ float2 Ug[NLAY * NQB][4];   // 2x2 unitaries, row-major
    __shared__ float2 Lt[16][16];          // current layer operator
    __shared__ float2 Mbuf[2][16][16];     // ping-pong accumulated M

    const int t = threadIdx.x;

    if (t < NLAY * NQB) {
        const float ang = angles[t];
        const float ax = gates[t * 3 + 0] * ang * 0.5f;
        const float ay = gates[t * 3 + 1] * ang * 0.5f;
        const float az = gates[t * 3 + 2] * ang * 0.5f;
        float sx, cx, sy, cy, sz, cz;
        sincosf(ax, &sx, &cx);
        sincosf(ay, &sy, &cy);
        sincosf(az, &sz, &cz);
        float2 RX[4] = {{cx, 0.f}, {0.f, -sx}, {0.f, -sx}, {cx, 0.f}};
        float2 RY[4] = {{cy, 0.f}, {-sy, 0.f}, {sy, 0.f}, {cy, 0.f}};
        float2 RZ[4] = {{cz, -sz}, {0.f, 0.f}, {0.f, 0.f}, {cz, sz}};
        float2 Mt[4], U[4];
        mm2(Mt, RY, RX);
        mm2(U, RZ, Mt);
        Ug[t][0] = U[0];
        Ug[t][1] = U[1];
        Ug[t][2] = U[2];
        Ug[t][3] = U[3];
    }

    const int o = t >> 4;        // output basis index
    const int j = t & 15;        // input basis index
    const int ao = (o >> 3) & 1, bo = (o >> 2) & 1, co = (o >> 1) & 1, dd = o & 1;
    const int aj = (j >> 3) & 1, bj = (j >> 2) & 1, cj = (j >> 1) & 1, dj = j & 1;
    const float sgn = ((SIGNMASK >> o) & 1u) ? -1.f : 1.f;

    // M = identity
    Mbuf[0][o][j] = make_float2((o == j) ? 1.f : 0.f, 0.f);
    __syncthreads();

    int cur = 0;
#pragma unroll 1
    for (int l = 0; l < NLAY; ++l) {
        // layer operator entry: CZsign(o) * prod_q Uq[outbit][inbit]
        const float2 k01 = cmul(Ug[l * 4 + 0][ao * 2 + aj], Ug[l * 4 + 1][bo * 2 + bj]);
        const float2 k23 = cmul(Ug[l * 4 + 2][co * 2 + cj], Ug[l * 4 + 3][dd * 2 + dj]);
        float2 e = cmul(k01, k23);
        e.x *= sgn;
        e.y *= sgn;
        Lt[o][j] = e;
        __syncthreads();

        // M_new = Lt * M_cur
        float2 acc = make_float2(0.f, 0.f);
#pragma unroll
        for (int k = 0; k < 16; ++k) {
            acc = cadd(acc, cmul(Lt[o][k], Mbuf[cur][k][j]));
        }
        Mbuf[cur ^ 1][o][j] = acc;
        cur ^= 1;
        __syncthreads();
    }

    M_out[o * 16 + j] = Mbuf[cur][o][j];
}

// ---- main: init product state, 16x16 matvec from LDS, Z expectations ----
__global__ __launch_bounds__(256) void qcnn_main_kernel(
    const float* __restrict__ images,   // [16,128,128,3]
    const float4* __restrict__ M4,      // [16][16] complex as 128 float4
    float* __restrict__ out)            // [16,127,127,4]
{
    __shared__ float4 Msh[128];   // 2 KB: M row-major, 2 complex per float4

    const int t = threadIdx.x;
    if (t < 128) Msh[t] = M4[t];
    __syncthreads();

    const int n = blockIdx.x * blockDim.x + t;
    if (n >= NPATCH) return;

    const int bimg = n / (DI * DJ);
    const int rem  = n - bimg * (DI * DJ);
    const int pi   = rem / DJ;
    const int pj   = rem - pi * DJ;

    const float* base = images + ((size_t)(bimg * HH + pi) * WW + pj) * 3;

    // per-qubit initial states from pixel RGB
    float2 S[NQB][2];
#pragma unroll
    for (int a = 0; a < 2; ++a) {
#pragma unroll
        for (int b = 0; b < 2; ++b) {
            const float* px = base + ((size_t)a * WW + b) * 3;
            const float d0 = px[0], d1 = px[1], d2 = px[2];
            const float al = 0.5f * (d0 + d2);   // (phi+omega)/(2*pi)
            const float be = 0.5f * (d2 - d0);   // (omega-phi)/(2*pi)
            const float th = 0.5f * d1;          // theta/(2*pi)
            float sa, ca, sb, cb, stt, ctt;
            sincospif(al, &sa, &ca);
            sincospif(be, &sb, &cb);
            sincospif(th, &stt, &ctt);
            const int q = a * 2 + b;
            S[q][0] = make_float2(ca * ctt, -sa * ctt);
            S[q][1] = make_float2(cb * stt,  sb * stt);
        }
    }

    // product state st = S0 (x) S1 (x) S2 (x) S3
    float2 st[16];
#pragma unroll
    for (int a = 0; a < 2; ++a) {
#pragma unroll
        for (int b = 0; b < 2; ++b) {
            const float2 ab = cmul(S[0][a], S[1][b]);
#pragma unroll
            for (int c = 0; c < 2; ++c) {
                const float2 abc = cmul(ab, S[2][c]);
#pragma unroll
                for (int d = 0; d < 2; ++d) {
                    st[a * 8 + b * 4 + c * 2 + d] = cmul(abc, S[3][d]);
                }
            }
        }
    }

    // y_o = sum_k M[o][k] * st[k]; probs + Z expectations on the fly.
    // M reads are uniform-address LDS broadcasts (no bank conflicts).
    float e0 = 0.f, e1 = 0.f, e2 = 0.f, e3 = 0.f;
#pragma unroll
    for (int o = 0; o < 16; ++o) {
        float accx = 0.f, accy = 0.f;
#pragma unroll
        for (int kk = 0; kk < 8; ++kk) {
            const float4 m = Msh[o * 8 + kk];   // {Re k, Im k, Re k+1, Im k+1}
            const float2 s0 = st[2 * kk];
            const float2 s1 = st[2 * kk + 1];
            accx = fmaf(m.x, s0.x, accx);
            accx = fmaf(-m.y, s0.y, accx);
            accy = fmaf(m.x, s0.y, accy);
            accy = fmaf(m.y, s0.x, accy);
            accx = fmaf(m.z, s1.x, accx);
            accx = fmaf(-m.w, s1.y, accx);
            accy = fmaf(m.z, s1.y, accy);
            accy = fmaf(m.w, s1.x, accy);
        }
        const float pr = fmaf(accx, accx, accy * accy);
        e0 += (o & 8) ? -pr : pr;
        e1 += (o & 4) ? -pr : pr;
        e2 += (o & 2) ? -pr : pr;
        e3 += (o & 1) ? -pr : pr;
    }

    float4 res = make_float4(e0, e1, e2, e3);
    *reinterpret_cast<float4*>(out + (size_t)n * 4) = res;
}

}  // namespace

extern "C" void kernel_launch(void* const* d_in, const int* in_sizes, int n_in,
                              void* d_out, int out_size, void* d_ws, size_t ws_size,
                              hipStream_t stream) {
    const float* images = (const float*)d_in[0];
    const float* gates  = (const float*)d_in[1];
    const float* angles = (const float*)d_in[2];
    float* out = (float*)d_out;
    float2* M = (float2*)d_ws;   // 16*16*8 = 2048 bytes

    build_M_kernel<<<1, 256, 0, stream>>>(gates, angles, M);

    const int block = 256;
    const int grid = (NPATCH + block - 1) / block;
    qcnn_main_kernel<<<grid, block, 0, stream>>>(images, (const float4*)M, out);
}

// Round 5
// 22.682 us; speedup vs baseline: 2.0709x; 1.0764x over previous
//
#include <hip/hip_runtime.h>
#include <math.h>

namespace {

typedef float f32x2 __attribute__((ext_vector_type(2)));

constexpr int NLAY = 10;
constexpr int NQB  = 4;
constexpr int NB   = 16;   // batch
constexpr int HH   = 128;
constexpr int WW   = 128;
constexpr int DI   = HH - 1;   // 127
constexpr int DJ   = WW - 1;   // 127
constexpr int NPATCH = NB * DI * DJ;   // 258064
constexpr int PPT  = 2;    // patches per thread

// Combined CZ(0,1)*CZ(2,3)*CZ(1,2) sign per basis index (bit3=a,...,bit0=d)
constexpr unsigned SIGNMASK = 0xB848u;

__device__ __forceinline__ float2 cmul(float2 a, float2 b) {
    return make_float2(fmaf(a.x, b.x, -a.y * b.y), fmaf(a.x, b.y, a.y * b.x));
}
__device__ __forceinline__ float2 cadd(float2 a, float2 b) {
    return make_float2(a.x + b.x, a.y + b.y);
}
__device__ __forceinline__ void mm2(float2* D, const float2* A, const float2* B) {
    D[0] = cadd(cmul(A[0], B[0]), cmul(A[1], B[2]));
    D[1] = cadd(cmul(A[0], B[1]), cmul(A[1], B[3]));
    D[2] = cadd(cmul(A[2], B[0]), cmul(A[3], B[2]));
    D[3] = cadd(cmul(A[2], B[1]), cmul(A[3], B[3]));
}

// packed complex FMA: acc.{lo,hi} += {Re,Im} of m*s  (2 x v_pk_fma_f32)
// lo: m.x*s.x - m.y*s.y ; hi: m.x*s.y + m.y*s.x   (same rounding order as scalar)
__device__ __forceinline__ void cfma_pk(f32x2& acc, f32x2 m, f32x2 s) {
    asm("v_pk_fma_f32 %0, %1, %2, %0 op_sel_hi:[0,1,1]\n\t"
        "v_pk_fma_f32 %0, %1, %2, %0 op_sel:[1,1,0] op_sel_hi:[1,0,1] neg_lo:[1,0,0]"
        : "+v"(acc) : "v"(m), "v"(s));
}

// packed complex multiply: c = a*b (2 instructions)
__device__ __forceinline__ f32x2 cmul_pk(f32x2 a, f32x2 b) {
    f32x2 c;
    asm("v_pk_mul_f32 %0, %1, %2 op_sel_hi:[0,1]\n\t"
        "v_pk_fma_f32 %0, %1, %2, %0 op_sel:[1,1,0] op_sel_hi:[1,0,1] neg_lo:[1,0,0]"
        : "=&v"(c) : "v"(a), "v"(b));
    return c;
}

// ---- setup: build full-circuit 16x16 unitary M, parallel over 256 threads --
__global__ __launch_bounds__(256) void build_M_kernel(
    const float* __restrict__ gates,    // [10,4,3] one-hot
    const float* __restrict__ angles,   // [10,4]
    float2* __restrict__ M_out)         // [16][16] row-major
{
    __shared__ float2 Ug[NLAY * NQB][4];   // 2x2 unitaries, row-major
    __shared__ float2 Lt[16][17];          // current layer operator (padded)
    __shared__ float2 Mbuf[2][16][17];     // ping-pong accumulated M (padded)

    const int t = threadIdx.x;

    if (t < NLAY * NQB) {
        const float ang = angles[t];
        const float ax = gates[t * 3 + 0] * ang * 0.5f;
        const float ay = gates[t * 3 + 1] * ang * 0.5f;
        const float az = gates[t * 3 + 2] * ang * 0.5f;
        float sx, cx, sy, cy, sz, cz;
        sincosf(ax, &sx, &cx);
        sincosf(ay, &sy, &cy);
        sincosf(az, &sz, &cz);
        float2 RX[4] = {{cx, 0.f}, {0.f, -sx}, {0.f, -sx}, {cx, 0.f}};
        float2 RY[4] = {{cy, 0.f}, {-sy, 0.f}, {sy, 0.f}, {cy, 0.f}};
        float2 RZ[4] = {{cz, -sz}, {0.f, 0.f}, {0.f, 0.f}, {cz, sz}};
        float2 Mt[4], U[4];
        mm2(Mt, RY, RX);
        mm2(U, RZ, Mt);
        Ug[t][0] = U[0];
        Ug[t][1] = U[1];
        Ug[t][2] = U[2];
        Ug[t][3] = U[3];
    }

    const int o = t >> 4;        // output basis index
    const int j = t & 15;        // input basis index
    const int ao = (o >> 3) & 1, bo = (o >> 2) & 1, co = (o >> 1) & 1, dd = o & 1;
    const int aj = (j >> 3) & 1, bj = (j >> 2) & 1, cj = (j >> 1) & 1, dj = j & 1;
    const float sgn = ((SIGNMASK >> o) & 1u) ? -1.f : 1.f;

    Mbuf[0][o][j] = make_float2((o == j) ? 1.f : 0.f, 0.f);
    __syncthreads();

    int cur = 0;
#pragma unroll 1
    for (int l = 0; l < NLAY; ++l) {
        const float2 k01 = cmul(Ug[l * 4 + 0][ao * 2 + aj], Ug[l * 4 + 1][bo * 2 + bj]);
        const float2 k23 = cmul(Ug[l * 4 + 2][co * 2 + cj], Ug[l * 4 + 3][dd * 2 + dj]);
        float2 e = cmul(k01, k23);
        e.x *= sgn;
        e.y *= sgn;
        Lt[o][j] = e;
        __syncthreads();

        float2 acc = make_float2(0.f, 0.f);
#pragma unroll
        for (int k = 0; k < 16; ++k) {
            acc = cadd(acc, cmul(Lt[o][k], Mbuf[cur][k][j]));
        }
        Mbuf[cur ^ 1][o][j] = acc;
        cur ^= 1;
        __syncthreads();
    }

    M_out[o * 16 + j] = Mbuf[cur][o][j];
}

// ---- main: 2 patches/thread, packed-fp32 16x16 matvec from LDS ----
__global__ __launch_bounds__(256) void qcnn_main_kernel(
    const float* __restrict__ images,   // [16,128,128,3]
    const float4* __restrict__ M4,      // [16][16] complex as 128 float4
    float* __restrict__ out)            // [16,127,127,4]
{
    __shared__ float4 Msh[128];   // 2 KB: M row-major, 2 complex per float4

    const int t = threadIdx.x;
    if (t < 128) Msh[t] = M4[t];
    __syncthreads();

    const int n_base = blockIdx.x * (256 * PPT) + t;

    // ---- per-patch initial states ----
    f32x2 st[PPT][16];
#pragma unroll
    for (int p = 0; p < PPT; ++p) {
        const int n = min(n_base + p * 256, NPATCH - 1);
        const int bimg = n / (DI * DJ);
        const int rem  = n - bimg * (DI * DJ);
        const int pi   = rem / DJ;
        const int pj   = rem - pi * DJ;
        const float* base = images + ((size_t)(bimg * HH + pi) * WW + pj) * 3;

        f32x2 S[NQB][2];
#pragma unroll
        for (int a = 0; a < 2; ++a) {
#pragma unroll
            for (int b = 0; b < 2; ++b) {
                const float* px = base + ((size_t)a * WW + b) * 3;
                const float d0 = px[0], d1 = px[1], d2 = px[2];
                const float al = 0.5f * (d0 + d2);
                const float be = 0.5f * (d2 - d0);
                const float th = 0.5f * d1;
                float sa, ca, sb, cb, stt, ctt;
                sincospif(al, &sa, &ca);
                sincospif(be, &sb, &cb);
                sincospif(th, &stt, &ctt);
                const int q = a * 2 + b;
                S[q][0] = f32x2{ca * ctt, -sa * ctt};
                S[q][1] = f32x2{cb * stt,  sb * stt};
            }
        }

#pragma unroll
        for (int a = 0; a < 2; ++a) {
#pragma unroll
            for (int b = 0; b < 2; ++b) {
                const f32x2 ab = cmul_pk(S[0][a], S[1][b]);
#pragma unroll
                for (int c = 0; c < 2; ++c) {
                    const f32x2 abc = cmul_pk(ab, S[2][c]);
#pragma unroll
                    for (int d = 0; d < 2; ++d) {
                        st[p][a * 8 + b * 4 + c * 2 + d] = cmul_pk(abc, S[3][d]);
                    }
                }
            }
        }
    }

    // ---- matvec + expectations; each M broadcast feeds both patches ----
    float e0[PPT], e1[PPT], e2[PPT], e3[PPT];
#pragma unroll
    for (int p = 0; p < PPT; ++p) { e0[p] = e1[p] = e2[p] = e3[p] = 0.f; }

#pragma unroll
    for (int o = 0; o < 16; ++o) {
        f32x2 acc[PPT];
#pragma unroll
        for (int p = 0; p < PPT; ++p) acc[p] = f32x2{0.f, 0.f};
#pragma unroll
        for (int kk = 0; kk < 8; ++kk) {
            const float4 m = Msh[o * 8 + kk];   // {Re k, Im k, Re k+1, Im k+1}
            const f32x2 mlo = {m.x, m.y};
            const f32x2 mhi = {m.z, m.w};
#pragma unroll
            for (int p = 0; p < PPT; ++p) {
                cfma_pk(acc[p], mlo, st[p][2 * kk]);
                cfma_pk(acc[p], mhi, st[p][2 * kk + 1]);
            }
        }
#pragma unroll
        for (int p = 0; p < PPT; ++p) {
            const float pr = fmaf(acc[p].x, acc[p].x, acc[p].y * acc[p].y);
            e0[p] += (o & 8) ? -pr : pr;
            e1[p] += (o & 4) ? -pr : pr;
            e2[p] += (o & 2) ? -pr : pr;
            e3[p] += (o & 1) ? -pr : pr;
        }
    }

#pragma unroll
    for (int p = 0; p < PPT; ++p) {
        const int n = n_base + p * 256;
        if (n < NPATCH) {
            float4 res = make_float4(e0[p], e1[p], e2[p], e3[p]);
            *reinterpret_cast<float4*>(out + (size_t)n * 4) = res;
        }
    }
}

}  // namespace

extern "C" void kernel_launch(void* const* d_in, const int* in_sizes, int n_in,
                              void* d_out, int out_size, void* d_ws, size_t ws_size,
                              hipStream_t stream) {
    const float* images = (const float*)d_in[0];
    const float* gates  = (const float*)d_in[1];
    const float* angles = (const float*)d_in[2];
    float* out = (float*)d_out;
    float2* M = (float2*)d_ws;   // 16*16*8 = 2048 bytes

    build_M_kernel<<<1, 256, 0, stream>>>(gates, angles, M);

    const int per_block = 256 * PPT;
    const int grid = (NPATCH + per_block - 1) / per_block;   // 505
    qcnn_main_kernel<<<grid, 256, 0, stream>>>(images, (const float4*)M, out);
}